// Round 13
// baseline (124.230 us; speedup 1.0000x reference)
//
#include <hip/hip_runtime.h>
#include <hip/hip_bf16.h>

#define BB  32
#define LHH 1024
#define LUU 128
#define HDD 256
#define NEGF (-1e30f)

typedef __attribute__((ext_vector_type(8))) short short8;
typedef __attribute__((ext_vector_type(4))) short short4v;
typedef __attribute__((ext_vector_type(4))) float f32x4;

// ---- workspace layout (float offsets) ----
static constexpr size_t P_OFF    = 0;                            // bf16 [B][LH][LU] P' = exp(S-rm)*ri
static constexpr size_t UWBP_OFF = P_OFF + (size_t)BB*LHH*LUU/2; // [B][8][LU] uwb partials
static constexpr size_t RM_OFF   = UWBP_OFF + (size_t)BB*8*LUU;  // [B][LH] row max
static constexpr size_t RI_OFF   = RM_OFF + (size_t)BB*LHH;      // [B][LH] 1/row sum
static constexpr size_t PM_OFF   = RI_OFF + (size_t)BB*LHH;      // [B][16][LU] col-max partials
static constexpr size_t PS_OFF   = PM_OFF + (size_t)BB*16*LUU;   // [B][16][LU] col-sum partials
static constexpr size_t CM_OFF   = PS_OFF + (size_t)BB*16*LUU;   // [B][LU] col max
static constexpr size_t CI_OFF   = CM_OFF + (size_t)BB*LUU;      // [B][LU] 1/col sum
static constexpr size_t UBT_OFF  = CI_OFF + (size_t)BB*LUU;      // bf16 [B][HD][LU] u^T
static constexpr size_t CBT_OFF  = UBT_OFF + (size_t)BB*HDD*LUU/2; // bf16 [B][HD][LU] C^T
static constexpr size_t VBF_OFF  = CBT_OFF + (size_t)BB*HDD*LUU/2; // bf16 [B][LU][HD] v
static constexpr size_t FLAG_OFF = VBF_OFF + (size_t)BB*LUU*HDD/2; // 1 int
static constexpr size_t WS_FLOATS= FLAG_OFF + 1;

__device__ __forceinline__ float mval(const void* p, int idx, int flag) {
    if (flag) return ((const unsigned char*)p)[idx] ? 1.0f : 0.0f;
    return (((const int*)p)[idx] != 0) ? 1.0f : 0.0f;
}
__device__ __forceinline__ float cexpf(float x) { return __expf(fminf(x, 60.0f)); }
__device__ __forceinline__ float grcp(float x)  { return 1.0f / fmaxf(x, 1e-38f); }
__device__ __forceinline__ int swz(int r) { return (r ^ (r >> 2)) & 3; }
__device__ __forceinline__ int swz8(int r) { return (r ^ (r >> 3)) & 7; }
__device__ __forceinline__ float b2f(short v) {
    return __uint_as_float(((unsigned)(unsigned short)v) << 16);
}
__device__ __forceinline__ short f2b(float x) {
    __hip_bfloat16 h = __float2bfloat16(x);
    return *reinterpret_cast<short*>(&h);
}

// ---- K0 (fused): reads u ONCE -> ubt (bf16 u^T), vbf (bf16 v), uwb partials, flag
__global__ __launch_bounds__(256) void k_prep(const float* __restrict__ u,
                                              const float* __restrict__ w,
                                              const unsigned char* __restrict__ hm,
                                              float* __restrict__ ws) {
    __shared__ float ls[32][132];
    int b = blockIdx.x, hd0 = blockIdx.y * 32;
    int t = threadIdx.x;
    if (blockIdx.x == 0 && blockIdx.y == 0 && t == 0)
        reinterpret_cast<int*>(ws)[FLAG_OFF] = (hm[1] != 0) ? 1 : 0;
    int hc = t & 7, jj = t >> 3;
    float4 whv  = *reinterpret_cast<const float4*>(w + hd0 + hc * 4);
    float4 wuv  = *reinterpret_cast<const float4*>(w + HDD + hd0 + hc * 4);
    float4 whuv = *reinterpret_cast<const float4*>(w + 2 * HDD + hd0 + hc * 4);
    short* vbf = reinterpret_cast<short*>(ws + VBF_OFF);
    #pragma unroll
    for (int pass = 0; pass < 4; ++pass) {
        int j = jj + pass * 32;
        float4 v = *reinterpret_cast<const float4*>(u + ((size_t)(b * LUU + j)) * HDD + hd0 + hc * 4);
        ls[hc * 4 + 0][j] = v.x; ls[hc * 4 + 1][j] = v.y;
        ls[hc * 4 + 2][j] = v.z; ls[hc * 4 + 3][j] = v.w;
        union { short4v s4; __hip_bfloat16 bh[4]; } pv;
        pv.bh[0] = __float2bfloat16(whv.x + whuv.x * v.x);
        pv.bh[1] = __float2bfloat16(whv.y + whuv.y * v.y);
        pv.bh[2] = __float2bfloat16(whv.z + whuv.z * v.z);
        pv.bh[3] = __float2bfloat16(whv.w + whuv.w * v.w);
        *reinterpret_cast<short4v*>(&vbf[((size_t)(b * LUU + j)) * HDD + hd0 + hc * 4]) = pv.s4;
        float s = v.x * wuv.x + v.y * wuv.y + v.z * wuv.z + v.w * wuv.w;
        s += __shfl_xor(s, 1); s += __shfl_xor(s, 2); s += __shfl_xor(s, 4);
        if (hc == 0) ws[UWBP_OFF + (b * 8 + blockIdx.y) * LUU + j] = s;
    }
    __syncthreads();
    int r = t >> 3, ck = t & 7;
    short* ubt = reinterpret_cast<short*>(ws + UBT_OFF);
    union { short8 s8; __hip_bfloat16 bh[8]; } pk;
    #pragma unroll
    for (int hhalf = 0; hhalf < 2; ++hhalf) {
        #pragma unroll
        for (int c = 0; c < 8; ++c)
            pk.bh[c] = __float2bfloat16(ls[r][ck * 16 + hhalf * 8 + c]);
        *reinterpret_cast<short8*>(&ubt[((size_t)(b * 256 + hd0 + r)) * 128 + ck * 16 + hhalf * 8]) = pk.s8;
    }
}

// -------- K1 (MFMA): S = h·v^T + uwb; write P' bf16; row stats; col partials --
__global__ __launch_bounds__(256) void k_Smfma(const float* __restrict__ h,
                                               const void* __restrict__ u_mask,
                                               const void* __restrict__ h_mask,
                                               const float* __restrict__ bias,
                                               float* __restrict__ ws) {
    __shared__ __align__(16) short lh[64 * 32];
    __shared__ __align__(16) short lv[128 * 32];
    __shared__ float uwb_l[128], um_l[128], hm_l[64];
    __shared__ float credm[4][128], creds[4][128];

    int b  = blockIdx.x;
    int i0 = blockIdx.y * 64;
    int t  = threadIdx.x;
    int flag = reinterpret_cast<const int*>(ws)[FLAG_OFF];
    int wave = t >> 6, lane = t & 63;
    int lj = lane & 15, lq = lane >> 4;

    if (t < 128) {
        float s = bias[0];
        #pragma unroll
        for (int c = 0; c < 8; ++c) s += ws[UWBP_OFF + (b * 8 + c) * LUU + t];
        uwb_l[t] = s;
        um_l[t]  = mval(u_mask, b * LUU + t, flag);
    } else if (t < 192) {
        hm_l[t - 128] = mval(h_mask, b * LHH + i0 + (t - 128), flag);
    }

    int hrow = t >> 2,  hc = t & 3,  hlc = hc ^ swz(hrow);
    int vrow0 = t >> 2, vc0 = t & 3, vlc0 = vc0 ^ swz(vrow0);
    int vrow1 = (t + 256) >> 2, vc1 = t & 3, vlc1 = vc1 ^ swz(vrow1);
    const float* hsrc = h + ((size_t)(b * LHH + i0 + hrow)) * HDD + hlc * 8;
    const short* vbf  = reinterpret_cast<const short*>(ws + VBF_OFF);
    const short* vsrc0 = vbf + ((size_t)(b * LUU + vrow0)) * HDD + vlc0 * 8;
    const short* vsrc1 = vbf + ((size_t)(b * LUU + vrow1)) * HDD + vlc1 * 8;

    int arow = wave * 16 + lj;
    int a_idx = arow * 32 + ((lq ^ swz(arow)) * 8);
    int b_idx[8];
    #pragma unroll
    for (int n = 0; n < 8; ++n) {
        int j = n * 16 + lj;
        b_idx[n] = j * 32 + ((lq ^ swz(j)) * 8);
    }

    f32x4 acc[8];
    #pragma unroll
    for (int n = 0; n < 8; ++n) acc[n] = (f32x4){0.f, 0.f, 0.f, 0.f};

    for (int step = 0; step < 8; ++step) {
        int k0 = step * 32;
        if (step) __syncthreads();
        {
            float4 f0 = *reinterpret_cast<const float4*>(hsrc + k0);
            float4 f1 = *reinterpret_cast<const float4*>(hsrc + k0 + 4);
            union { short8 s8; __hip_bfloat16 bh[8]; } pk;
            pk.bh[0]=__float2bfloat16(f0.x); pk.bh[1]=__float2bfloat16(f0.y);
            pk.bh[2]=__float2bfloat16(f0.z); pk.bh[3]=__float2bfloat16(f0.w);
            pk.bh[4]=__float2bfloat16(f1.x); pk.bh[5]=__float2bfloat16(f1.y);
            pk.bh[6]=__float2bfloat16(f1.z); pk.bh[7]=__float2bfloat16(f1.w);
            *reinterpret_cast<short8*>(&lh[hrow * 32 + hc * 8]) = pk.s8;
        }
        *reinterpret_cast<short8*>(&lv[vrow0 * 32 + vc0 * 8]) =
            *reinterpret_cast<const short8*>(vsrc0 + k0);
        *reinterpret_cast<short8*>(&lv[vrow1 * 32 + vc1 * 8]) =
            *reinterpret_cast<const short8*>(vsrc1 + k0);
        __syncthreads();
        short8 af = *reinterpret_cast<const short8*>(&lh[a_idx]);
        #pragma unroll
        for (int n = 0; n < 8; ++n) {
            short8 bf = *reinterpret_cast<const short8*>(&lv[b_idx[n]]);
            acc[n] = __builtin_amdgcn_mfma_f32_16x16x32_bf16(af, bf, acc[n], 0, 0, 0);
        }
    }

    // ---- epilogue 1: add uwb, row stats, write P' = bf16(exp(S-rm)*ri) ----
    float sv[8][4];
    #pragma unroll
    for (int n = 0; n < 8; ++n) {
        float uw = uwb_l[n * 16 + lj];
        #pragma unroll
        for (int q = 0; q < 4; ++q) sv[n][q] = acc[n][q] + uw;
    }
    float umv[8];
    #pragma unroll
    for (int n = 0; n < 8; ++n) umv[n] = um_l[n * 16 + lj];

    short* Pg = reinterpret_cast<short*>(ws + P_OFF);
    #pragma unroll
    for (int q = 0; q < 4; ++q) {
        float ms = NEGF;
        #pragma unroll
        for (int n = 0; n < 8; ++n) ms = fmaxf(ms, umv[n] > 0.f ? sv[n][q] : NEGF);
        #pragma unroll
        for (int off = 8; off; off >>= 1) ms = fmaxf(ms, __shfl_xor(ms, off));
        float pe[8], e = 0.f;
        #pragma unroll
        for (int n = 0; n < 8; ++n) { pe[n] = cexpf(sv[n][q] - ms); e += umv[n] * pe[n]; }
        #pragma unroll
        for (int off = 8; off; off >>= 1) e += __shfl_xor(e, off);
        float riv = grcp(e);
        int i = i0 + wave * 16 + lq * 4 + q;
        short* Prow = Pg + ((size_t)(b * LHH + i)) * LUU;
        #pragma unroll
        for (int n = 0; n < 8; ++n) Prow[n * 16 + lj] = f2b(pe[n] * riv);
        if (lj == 0) {
            ws[RM_OFF + b * LHH + i] = ms;
            ws[RI_OFF + b * LHH + i] = riv;
        }
    }

    // ---- epilogue 2: col-stat partials over this block's 64 i-rows ----
    float hmq[4];
    #pragma unroll
    for (int q = 0; q < 4; ++q) hmq[q] = hm_l[wave * 16 + lq * 4 + q];
    #pragma unroll
    for (int n = 0; n < 8; ++n) {
        float cmx = NEGF, csx = 0.f;
        #pragma unroll
        for (int q = 0; q < 4; ++q) {
            if (hmq[q] > 0.f) {
                float x  = sv[n][q];
                float mn = fmaxf(cmx, x);
                csx = csx * cexpf(cmx - mn) + cexpf(x - mn);
                cmx = mn;
            }
        }
        #pragma unroll
        for (int off = 16; off <= 32; off <<= 1) {
            float om = __shfl_xor(cmx, off);
            float os = __shfl_xor(csx, off);
            float mn = fmaxf(cmx, om);
            csx = csx * cexpf(cmx - mn) + os * cexpf(om - mn);
            cmx = mn;
        }
        if (lq == 0) { credm[wave][n * 16 + lj] = cmx; creds[wave][n * 16 + lj] = csx; }
    }
    __syncthreads();
    if (t < 128) {
        float m = credm[0][t], s = creds[0][t];
        #pragma unroll
        for (int wv = 1; wv < 4; ++wv) {
            float om = credm[wv][t], os = creds[wv][t];
            float mn = fmaxf(m, om);
            s = s * cexpf(m - mn) + os * cexpf(om - mn);
            m = mn;
        }
        ws[PM_OFF + (b * 16 + blockIdx.y) * LUU + t] = m;
        ws[PS_OFF + (b * 16 + blockIdx.y) * LUU + t] = s;
    }
}

// ---- K3 (MFMA): C^T[hd][u] = um_u · Σ_i h[i,hd]·P'[i,u] -> bf16 -------------
// grid (B, 4 hd-quarters, 2 u-halves) = 256 blocks. i-step 64 (16 steps, 32
// barriers vs 64 before); [64][64] LDS tiles with 8-chunk swizzle swz8 (2-way
// = free). MFMA order over i unchanged -> bitwise-identical accumulation.
__global__ __launch_bounds__(256) void k_Cmfma(const float* __restrict__ h,
                                               const void* __restrict__ u_mask,
                                               float* __restrict__ ws) {
    __shared__ __align__(16) short lha[64 * 64];    // [hd][i] 8 KB
    __shared__ __align__(16) short lsa[64 * 64];    // [u][i]  8 KB
    __shared__ float um_s[64];
    int b = blockIdx.x, hd0 = blockIdx.y * 64, u0 = blockIdx.z * 64;
    int t = threadIdx.x;
    int flag = reinterpret_cast<const int*>(ws)[FLAG_OFF];

    if (t < 64) um_s[t] = mval(u_mask, b * LUU + u0 + t, flag);

    if (blockIdx.y == 0 && blockIdx.z == 0 && t >= 64 && t < 192) {  // folded colcomb
        int j = t - 64;
        float m = NEGF;
        #pragma unroll
        for (int c = 0; c < 16; ++c) m = fmaxf(m, ws[PM_OFF + (b * 16 + c) * LUU + j]);
        float s = 0.f;
        #pragma unroll
        for (int c = 0; c < 16; ++c)
            s += ws[PS_OFF + (b * 16 + c) * LUU + j] * cexpf(ws[PM_OFF + (b * 16 + c) * LUU + j] - m);
        ws[CM_OFF + b * LUU + j] = m;
        ws[CI_OFF + b * LUU + j] = grcp(s);
    }

    int wave = t >> 6, lane = t & 63, lj = lane & 15, lq = lane >> 4;

    // staging: 2 chunks/thread per tile; chunk id ch = t + cc*256
    // row = ch>>3 (0..63), phys chunk c8 = ch&7, logical l8 = c8 ^ swz8(row)
    int srow[2], sc8[2], sl8[2];
    #pragma unroll
    for (int cc = 0; cc < 2; ++cc) {
        int ch = t + cc * 256;
        srow[cc] = ch >> 3; sc8[cc] = ch & 7; sl8[cc] = sc8[cc] ^ swz8(srow[cc]);
    }
    const float* hb = h + (size_t)b * LHH * HDD + hd0;
    const short* Pb = reinterpret_cast<const short*>(ws + P_OFF) + (size_t)b * LHH * LUU + u0;

    // fragment read indices (per kk half)
    int arow = wave * 16 + lj;
    int a_idx[2], b_idx[2][4];
    #pragma unroll
    for (int kk = 0; kk < 2; ++kk) {
        a_idx[kk] = arow * 64 + (((kk * 4 + lq) ^ swz8(arow)) * 8);
        #pragma unroll
        for (int n = 0; n < 4; ++n) {
            int row = n * 16 + lj;
            b_idx[kk][n] = row * 64 + (((kk * 4 + lq) ^ swz8(row)) * 8);
        }
    }

    f32x4 acc[4];
    #pragma unroll
    for (int n = 0; n < 4; ++n) acc[n] = (f32x4){0.f, 0.f, 0.f, 0.f};

    for (int step = 0; step < 16; ++step) {
        int i0 = step * 64;
        if (step) __syncthreads();
        #pragma unroll
        for (int cc = 0; cc < 2; ++cc) {
            int row = srow[cc];
            {   // stage h^T chunk: logical i-chunk sl8 at phys sc8
                union { short8 s8; __hip_bfloat16 bh[8]; } pk;
                #pragma unroll
                for (int e = 0; e < 8; ++e)
                    pk.bh[e] = __float2bfloat16(hb[(size_t)(i0 + sl8[cc] * 8 + e) * HDD + row]);
                *reinterpret_cast<short8*>(&lha[row * 64 + sc8[cc] * 8]) = pk.s8;
            }
            {   // stage P'^T chunk (pure short gather)
                short8 ps;
                #pragma unroll
                for (int e = 0; e < 8; ++e)
                    ps[e] = Pb[(size_t)(i0 + sl8[cc] * 8 + e) * LUU + row];
                *reinterpret_cast<short8*>(&lsa[row * 64 + sc8[cc] * 8]) = ps;
            }
        }
        __syncthreads();
        #pragma unroll
        for (int kk = 0; kk < 2; ++kk) {
            short8 af = *reinterpret_cast<const short8*>(&lha[a_idx[kk]]);
            #pragma unroll
            for (int n = 0; n < 4; ++n) {
                short8 bf = *reinterpret_cast<const short8*>(&lsa[b_idx[kk][n]]);
                acc[n] = __builtin_amdgcn_mfma_f32_16x16x32_bf16(af, bf, acc[n], 0, 0, 0);
            }
        }
    }

    __hip_bfloat16* cbt = reinterpret_cast<__hip_bfloat16*>(ws + CBT_OFF);
    #pragma unroll
    for (int q = 0; q < 4; ++q) {
        int hd = hd0 + wave * 16 + lq * 4 + q;
        #pragma unroll
        for (int n = 0; n < 4; ++n) {
            int uu = n * 16 + lj;
            cbt[(size_t)(b * 256 + hd) * 128 + u0 + uu] =
                __float2bfloat16(acc[n][q] * um_s[uu]);
        }
    }
}

// ---------------- K4 (MFMA): U=a_t·u, H=b_t·C, concat output ----------------
// a_t = P'·um_j ; b_t = P'·R2_i·Cc_j with R2 = hm·e^{rm}/ri, Cc = e^{-cm}·ci
__global__ __launch_bounds__(256) void k_outm(const float* __restrict__ h,
                                              const void* __restrict__ h_mask,
                                              const void* __restrict__ u_mask,
                                              const float* __restrict__ ws,
                                              float* __restrict__ out) {
    __shared__ __align__(16) short la[64 * 32], lb[64 * 32];
    __shared__ __align__(16) short lu[128 * 32], lc[128 * 32];
    __shared__ float R2_l[64];
    __shared__ float um_l[128], Cc_l[128];

    int b = blockIdx.x, i0 = blockIdx.y * 64, hd0 = blockIdx.z * 128;
    int t = threadIdx.x;
    int flag = reinterpret_cast<const int*>(ws)[FLAG_OFF];
    int wave = t >> 6, lane = t & 63, lj = lane & 15, lq = lane >> 4;

    if (t < 64) {
        float rmv = ws[RM_OFF + b * LHH + i0 + t];
        float riv = ws[RI_OFF + b * LHH + i0 + t];
        R2_l[t] = mval(h_mask, b * LHH + i0 + t, flag) * cexpf(rmv) / riv;
    } else if (t < 192) {
        int j = t - 64;
        float cmv = ws[CM_OFF + b * LUU + j];
        Cc_l[j] = cexpf(-cmv) * ws[CI_OFF + b * LUU + j];
        um_l[j] = mval(u_mask, b * LUU + j, flag);
    }

    const short* Pbase = reinterpret_cast<const short*>(ws + P_OFF) + (size_t)b * LHH * LUU;
    const short* ubt = reinterpret_cast<const short*>(ws + UBT_OFF) + ((size_t)(b * 256 + hd0)) * 128;
    const short* cbt = reinterpret_cast<const short*>(ws + CBT_OFF) + ((size_t)(b * 256 + hd0)) * 128;

    int air = t >> 2, ap = t & 3;
    int brow = t >> 1;
    int a_idx = (wave * 16 + lj) * 32 + ((lq ^ swz(wave * 16 + lj)) * 8);
    int b_idx[8];
    #pragma unroll
    for (int n = 0; n < 8; ++n) {
        int r = n * 16 + lj;
        b_idx[n] = r * 32 + ((lq ^ swz(r)) * 8);
    }

    f32x4 aU[8], aH[8];
    #pragma unroll
    for (int n = 0; n < 8; ++n) { aU[n] = (f32x4){0,0,0,0}; aH[n] = (f32x4){0,0,0,0}; }

    for (int step = 0; step < 4; ++step) {
        int j0 = step * 32;
        __syncthreads();
        {
            int lgc = ap ^ swz(air);
            short8 pv8 = *reinterpret_cast<const short8*>(
                Pbase + (size_t)(i0 + air) * LUU + j0 + lgc * 8);
            float R2v = R2_l[air];
            union { short8 s8; __hip_bfloat16 bh[8]; } pa, pb;
            #pragma unroll
            for (int c = 0; c < 8; ++c) {
                int j = j0 + lgc * 8 + c;
                float p = b2f(pv8[c]);
                pa.bh[c] = __float2bfloat16(p * um_l[j]);
                pb.bh[c] = __float2bfloat16(p * R2v * Cc_l[j]);
            }
            *reinterpret_cast<short8*>(&la[air * 32 + ap * 8]) = pa.s8;
            *reinterpret_cast<short8*>(&lb[air * 32 + ap * 8]) = pb.s8;
        }
        #pragma unroll
        for (int pp = 0; pp < 2; ++pp) {
            int p = (t & 1) * 2 + pp;
            int lgc = p ^ swz(brow);
            *reinterpret_cast<short8*>(&lu[brow * 32 + p * 8]) =
                *reinterpret_cast<const short8*>(ubt + (size_t)brow * 128 + j0 + lgc * 8);
            *reinterpret_cast<short8*>(&lc[brow * 32 + p * 8]) =
                *reinterpret_cast<const short8*>(cbt + (size_t)brow * 128 + j0 + lgc * 8);
        }
        __syncthreads();
        short8 fa = *reinterpret_cast<const short8*>(&la[a_idx]);
        short8 fb = *reinterpret_cast<const short8*>(&lb[a_idx]);
        #pragma unroll
        for (int n = 0; n < 8; ++n) {
            short8 gu = *reinterpret_cast<const short8*>(&lu[b_idx[n]]);
            short8 gc = *reinterpret_cast<const short8*>(&lc[b_idx[n]]);
            aU[n] = __builtin_amdgcn_mfma_f32_16x16x32_bf16(fa, gu, aU[n], 0, 0, 0);
            aH[n] = __builtin_amdgcn_mfma_f32_16x16x32_bf16(fb, gc, aH[n], 0, 0, 0);
        }
    }

    #pragma unroll
    for (int n = 0; n < 8; ++n) {
        int hd = hd0 + n * 16 + lj;
        #pragma unroll
        for (int q = 0; q < 4; ++q) {
            int i = i0 + wave * 16 + lq * 4 + q;
            float hv = h[((size_t)(b * LHH + i)) * HDD + hd];
            size_t base = ((size_t)(b * LHH + i)) * (4 * HDD) + hd;
            float Uv = aU[n][q], Hv = aH[n][q];
            out[base]           = hv;
            out[base + HDD]     = Uv;
            out[base + 2 * HDD] = hv * Uv;
            out[base + 3 * HDD] = hv * Hv;
        }
    }
}

extern "C" void kernel_launch(void* const* d_in, const int* in_sizes, int n_in,
                              void* d_out, int out_size, void* d_ws, size_t ws_size,
                              hipStream_t stream) {
    const float* h = (const float*)d_in[0];
    const float* u = (const float*)d_in[1];
    const void*  h_mask = d_in[2];
    const void*  u_mask = d_in[3];
    const float* w    = (const float*)d_in[4];
    const float* bias = (const float*)d_in[5];
    float* ws  = (float*)d_ws;
    float* out = (float*)d_out;

    if (ws_size < WS_FLOATS * sizeof(float)) return;  // diagnostic: leaves out zeroed

    k_prep<<<dim3(BB, HDD / 32), 256, 0, stream>>>(u, w, (const unsigned char*)h_mask, ws);
    k_Smfma<<<dim3(BB, LHH / 64), 256, 0, stream>>>(h, u_mask, h_mask, bias, ws);
    k_Cmfma<<<dim3(BB, 4, 2), 256, 0, stream>>>(h, u_mask, ws);
    k_outm<<<dim3(BB, LHH / 64, 2), 256, 0, stream>>>(h, h_mask, u_mask, ws, out);
}

// Round 14
// 83.723 us; speedup vs baseline: 1.4838x; 1.4838x over previous
//
#include <hip/hip_runtime.h>
#include <hip/hip_bf16.h>

#define BB  32
#define LHH 1024
#define LUU 128
#define HDD 256
#define NEGF (-1e30f)

typedef __attribute__((ext_vector_type(8))) short short8;
typedef __attribute__((ext_vector_type(4))) short short4v;
typedef __attribute__((ext_vector_type(4))) float f32x4;

// ---- workspace layout (float offsets) ----
static constexpr size_t P_OFF    = 0;                            // bf16 [B][LH][LU] P' = exp(S-rm)*ri
static constexpr size_t UWBP_OFF = P_OFF + (size_t)BB*LHH*LUU/2; // [B][8][LU] uwb partials
static constexpr size_t RM_OFF   = UWBP_OFF + (size_t)BB*8*LUU;  // [B][LH] row max
static constexpr size_t RI_OFF   = RM_OFF + (size_t)BB*LHH;      // [B][LH] 1/row sum
static constexpr size_t PM_OFF   = RI_OFF + (size_t)BB*LHH;      // [B][16][LU] col-max partials
static constexpr size_t PS_OFF   = PM_OFF + (size_t)BB*16*LUU;   // [B][16][LU] col-sum partials
static constexpr size_t CM_OFF   = PS_OFF + (size_t)BB*16*LUU;   // [B][LU] col max
static constexpr size_t CI_OFF   = CM_OFF + (size_t)BB*LUU;      // [B][LU] 1/col sum
static constexpr size_t UBT_OFF  = CI_OFF + (size_t)BB*LUU;      // bf16 [B][HD][LU] u^T
static constexpr size_t CBT_OFF  = UBT_OFF + (size_t)BB*HDD*LUU/2; // bf16 [B][HD][LU] C^T
static constexpr size_t VBF_OFF  = CBT_OFF + (size_t)BB*HDD*LUU/2; // bf16 [B][LU][HD] v
static constexpr size_t FLAG_OFF = VBF_OFF + (size_t)BB*LUU*HDD/2; // 1 int
static constexpr size_t WS_FLOATS= FLAG_OFF + 1;

__device__ __forceinline__ float mval(const void* p, int idx, int flag) {
    if (flag) return ((const unsigned char*)p)[idx] ? 1.0f : 0.0f;
    return (((const int*)p)[idx] != 0) ? 1.0f : 0.0f;
}
__device__ __forceinline__ float cexpf(float x) { return __expf(fminf(x, 60.0f)); }
__device__ __forceinline__ float grcp(float x)  { return 1.0f / fmaxf(x, 1e-38f); }
__device__ __forceinline__ int swz(int r) { return (r ^ (r >> 2)) & 3; }
__device__ __forceinline__ float b2f(short v) {
    return __uint_as_float(((unsigned)(unsigned short)v) << 16);
}
__device__ __forceinline__ short f2b(float x) {
    __hip_bfloat16 h = __float2bfloat16(x);
    return *reinterpret_cast<short*>(&h);
}

// ---- K0 (fused): reads u ONCE -> ubt (bf16 u^T), vbf (bf16 v), uwb partials, flag
__global__ __launch_bounds__(256) void k_prep(const float* __restrict__ u,
                                              const float* __restrict__ w,
                                              const unsigned char* __restrict__ hm,
                                              float* __restrict__ ws) {
    __shared__ float ls[32][132];
    int b = blockIdx.x, hd0 = blockIdx.y * 32;
    int t = threadIdx.x;
    if (blockIdx.x == 0 && blockIdx.y == 0 && t == 0)
        reinterpret_cast<int*>(ws)[FLAG_OFF] = (hm[1] != 0) ? 1 : 0;
    int hc = t & 7, jj = t >> 3;
    float4 whv  = *reinterpret_cast<const float4*>(w + hd0 + hc * 4);
    float4 wuv  = *reinterpret_cast<const float4*>(w + HDD + hd0 + hc * 4);
    float4 whuv = *reinterpret_cast<const float4*>(w + 2 * HDD + hd0 + hc * 4);
    short* vbf = reinterpret_cast<short*>(ws + VBF_OFF);
    #pragma unroll
    for (int pass = 0; pass < 4; ++pass) {
        int j = jj + pass * 32;
        float4 v = *reinterpret_cast<const float4*>(u + ((size_t)(b * LUU + j)) * HDD + hd0 + hc * 4);
        ls[hc * 4 + 0][j] = v.x; ls[hc * 4 + 1][j] = v.y;
        ls[hc * 4 + 2][j] = v.z; ls[hc * 4 + 3][j] = v.w;
        union { short4v s4; __hip_bfloat16 bh[4]; } pv;
        pv.bh[0] = __float2bfloat16(whv.x + whuv.x * v.x);
        pv.bh[1] = __float2bfloat16(whv.y + whuv.y * v.y);
        pv.bh[2] = __float2bfloat16(whv.z + whuv.z * v.z);
        pv.bh[3] = __float2bfloat16(whv.w + whuv.w * v.w);
        *reinterpret_cast<short4v*>(&vbf[((size_t)(b * LUU + j)) * HDD + hd0 + hc * 4]) = pv.s4;
        float s = v.x * wuv.x + v.y * wuv.y + v.z * wuv.z + v.w * wuv.w;
        s += __shfl_xor(s, 1); s += __shfl_xor(s, 2); s += __shfl_xor(s, 4);
        if (hc == 0) ws[UWBP_OFF + (b * 8 + blockIdx.y) * LUU + j] = s;
    }
    __syncthreads();
    int r = t >> 3, ck = t & 7;
    short* ubt = reinterpret_cast<short*>(ws + UBT_OFF);
    union { short8 s8; __hip_bfloat16 bh[8]; } pk;
    #pragma unroll
    for (int hhalf = 0; hhalf < 2; ++hhalf) {
        #pragma unroll
        for (int c = 0; c < 8; ++c)
            pk.bh[c] = __float2bfloat16(ls[r][ck * 16 + hhalf * 8 + c]);
        *reinterpret_cast<short8*>(&ubt[((size_t)(b * 256 + hd0 + r)) * 128 + ck * 16 + hhalf * 8]) = pk.s8;
    }
}

// -------- K1 (MFMA): S = h·v^T + uwb; write P' bf16; row stats; col partials --
__global__ __launch_bounds__(256) void k_Smfma(const float* __restrict__ h,
                                               const void* __restrict__ u_mask,
                                               const void* __restrict__ h_mask,
                                               const float* __restrict__ bias,
                                               float* __restrict__ ws) {
    __shared__ __align__(16) short lh[64 * 32];
    __shared__ __align__(16) short lv[128 * 32];
    __shared__ float uwb_l[128], um_l[128], hm_l[64];
    __shared__ float credm[4][128], creds[4][128];

    int b  = blockIdx.x;
    int i0 = blockIdx.y * 64;
    int t  = threadIdx.x;
    int flag = reinterpret_cast<const int*>(ws)[FLAG_OFF];
    int wave = t >> 6, lane = t & 63;
    int lj = lane & 15, lq = lane >> 4;

    if (t < 128) {
        float s = bias[0];
        #pragma unroll
        for (int c = 0; c < 8; ++c) s += ws[UWBP_OFF + (b * 8 + c) * LUU + t];
        uwb_l[t] = s;
        um_l[t]  = mval(u_mask, b * LUU + t, flag);
    } else if (t < 192) {
        hm_l[t - 128] = mval(h_mask, b * LHH + i0 + (t - 128), flag);
    }

    int hrow = t >> 2,  hc = t & 3,  hlc = hc ^ swz(hrow);
    int vrow0 = t >> 2, vc0 = t & 3, vlc0 = vc0 ^ swz(vrow0);
    int vrow1 = (t + 256) >> 2, vc1 = t & 3, vlc1 = vc1 ^ swz(vrow1);
    const float* hsrc = h + ((size_t)(b * LHH + i0 + hrow)) * HDD + hlc * 8;
    const short* vbf  = reinterpret_cast<const short*>(ws + VBF_OFF);
    const short* vsrc0 = vbf + ((size_t)(b * LUU + vrow0)) * HDD + vlc0 * 8;
    const short* vsrc1 = vbf + ((size_t)(b * LUU + vrow1)) * HDD + vlc1 * 8;

    int arow = wave * 16 + lj;
    int a_idx = arow * 32 + ((lq ^ swz(arow)) * 8);
    int b_idx[8];
    #pragma unroll
    for (int n = 0; n < 8; ++n) {
        int j = n * 16 + lj;
        b_idx[n] = j * 32 + ((lq ^ swz(j)) * 8);
    }

    f32x4 acc[8];
    #pragma unroll
    for (int n = 0; n < 8; ++n) acc[n] = (f32x4){0.f, 0.f, 0.f, 0.f};

    for (int step = 0; step < 8; ++step) {
        int k0 = step * 32;
        if (step) __syncthreads();
        {
            float4 f0 = *reinterpret_cast<const float4*>(hsrc + k0);
            float4 f1 = *reinterpret_cast<const float4*>(hsrc + k0 + 4);
            union { short8 s8; __hip_bfloat16 bh[8]; } pk;
            pk.bh[0]=__float2bfloat16(f0.x); pk.bh[1]=__float2bfloat16(f0.y);
            pk.bh[2]=__float2bfloat16(f0.z); pk.bh[3]=__float2bfloat16(f0.w);
            pk.bh[4]=__float2bfloat16(f1.x); pk.bh[5]=__float2bfloat16(f1.y);
            pk.bh[6]=__float2bfloat16(f1.z); pk.bh[7]=__float2bfloat16(f1.w);
            *reinterpret_cast<short8*>(&lh[hrow * 32 + hc * 8]) = pk.s8;
        }
        *reinterpret_cast<short8*>(&lv[vrow0 * 32 + vc0 * 8]) =
            *reinterpret_cast<const short8*>(vsrc0 + k0);
        *reinterpret_cast<short8*>(&lv[vrow1 * 32 + vc1 * 8]) =
            *reinterpret_cast<const short8*>(vsrc1 + k0);
        __syncthreads();
        short8 af = *reinterpret_cast<const short8*>(&lh[a_idx]);
        #pragma unroll
        for (int n = 0; n < 8; ++n) {
            short8 bf = *reinterpret_cast<const short8*>(&lv[b_idx[n]]);
            acc[n] = __builtin_amdgcn_mfma_f32_16x16x32_bf16(af, bf, acc[n], 0, 0, 0);
        }
    }

    // ---- epilogue 1: add uwb, row stats, write P' = bf16(exp(S-rm)*ri) ----
    float sv[8][4];
    #pragma unroll
    for (int n = 0; n < 8; ++n) {
        float uw = uwb_l[n * 16 + lj];
        #pragma unroll
        for (int q = 0; q < 4; ++q) sv[n][q] = acc[n][q] + uw;
    }
    float umv[8];
    #pragma unroll
    for (int n = 0; n < 8; ++n) umv[n] = um_l[n * 16 + lj];

    short* Pg = reinterpret_cast<short*>(ws + P_OFF);
    #pragma unroll
    for (int q = 0; q < 4; ++q) {
        float ms = NEGF;
        #pragma unroll
        for (int n = 0; n < 8; ++n) ms = fmaxf(ms, umv[n] > 0.f ? sv[n][q] : NEGF);
        #pragma unroll
        for (int off = 8; off; off >>= 1) ms = fmaxf(ms, __shfl_xor(ms, off));
        float pe[8], e = 0.f;
        #pragma unroll
        for (int n = 0; n < 8; ++n) { pe[n] = cexpf(sv[n][q] - ms); e += umv[n] * pe[n]; }
        #pragma unroll
        for (int off = 8; off; off >>= 1) e += __shfl_xor(e, off);
        float riv = grcp(e);
        int i = i0 + wave * 16 + lq * 4 + q;
        short* Prow = Pg + ((size_t)(b * LHH + i)) * LUU;
        #pragma unroll
        for (int n = 0; n < 8; ++n) Prow[n * 16 + lj] = f2b(pe[n] * riv);
        if (lj == 0) {
            ws[RM_OFF + b * LHH + i] = ms;
            ws[RI_OFF + b * LHH + i] = riv;
        }
    }

    // ---- epilogue 2: col-stat partials over this block's 64 i-rows ----
    float hmq[4];
    #pragma unroll
    for (int q = 0; q < 4; ++q) hmq[q] = hm_l[wave * 16 + lq * 4 + q];
    #pragma unroll
    for (int n = 0; n < 8; ++n) {
        float cmx = NEGF, csx = 0.f;
        #pragma unroll
        for (int q = 0; q < 4; ++q) {
            if (hmq[q] > 0.f) {
                float x  = sv[n][q];
                float mn = fmaxf(cmx, x);
                csx = csx * cexpf(cmx - mn) + cexpf(x - mn);
                cmx = mn;
            }
        }
        #pragma unroll
        for (int off = 16; off <= 32; off <<= 1) {
            float om = __shfl_xor(cmx, off);
            float os = __shfl_xor(csx, off);
            float mn = fmaxf(cmx, om);
            csx = csx * cexpf(cmx - mn) + os * cexpf(om - mn);
            cmx = mn;
        }
        if (lq == 0) { credm[wave][n * 16 + lj] = cmx; creds[wave][n * 16 + lj] = csx; }
    }
    __syncthreads();
    if (t < 128) {
        float m = credm[0][t], s = creds[0][t];
        #pragma unroll
        for (int wv = 1; wv < 4; ++wv) {
            float om = credm[wv][t], os = creds[wv][t];
            float mn = fmaxf(m, om);
            s = s * cexpf(m - mn) + os * cexpf(om - mn);
            m = mn;
        }
        ws[PM_OFF + (b * 16 + blockIdx.y) * LUU + t] = m;
        ws[PS_OFF + (b * 16 + blockIdx.y) * LUU + t] = s;
    }
}

// ---- K3 (MFMA): C^T[hd][u] = um_u · Σ_i h[i,hd]·P'[i,u] -> bf16 -------------
// grid (B, 4 hd-quarters, 2 u-halves) = 256 blocks (full machine).
__global__ __launch_bounds__(256) void k_Cmfma(const float* __restrict__ h,
                                               const void* __restrict__ u_mask,
                                               float* __restrict__ ws) {
    __shared__ __align__(16) short lha[64 * 32];    // h^T tile (64 hd x 32 i)
    __shared__ __align__(16) short lsa[64 * 32];    // P'^T tile (64 u x 32 i)
    __shared__ float um_s[64];
    int b = blockIdx.x, hd0 = blockIdx.y * 64, u0 = blockIdx.z * 64;
    int t = threadIdx.x;
    int flag = reinterpret_cast<const int*>(ws)[FLAG_OFF];

    if (t < 64) um_s[t] = mval(u_mask, b * LUU + u0 + t, flag);

    if (blockIdx.y == 0 && blockIdx.z == 0 && t >= 64 && t < 192) {  // folded colcomb
        int j = t - 64;
        float m = NEGF;
        #pragma unroll
        for (int c = 0; c < 16; ++c) m = fmaxf(m, ws[PM_OFF + (b * 16 + c) * LUU + j]);
        float s = 0.f;
        #pragma unroll
        for (int c = 0; c < 16; ++c)
            s += ws[PS_OFF + (b * 16 + c) * LUU + j] * cexpf(ws[PM_OFF + (b * 16 + c) * LUU + j] - m);
        ws[CM_OFF + b * LUU + j] = m;
        ws[CI_OFF + b * LUU + j] = grcp(s);
    }

    int wave = t >> 6, lane = t & 63, lj = lane & 15, lq = lane >> 4;
    int hd_r = t >> 2, ac = t & 3;             // A staging: row 0..63, chunk 0..3
    int u_r = t & 63, bc = t >> 6;             // B staging: row 0..63, chunk 0..3
    const float* hbp = h + (size_t)b * LHH * HDD + hd0 + hd_r;
    const short* Pbp = reinterpret_cast<const short*>(ws + P_OFF) + (size_t)b * LHH * LUU + u0 + u_r;

    int arow = wave * 16 + lj;
    int a_idx = arow * 32 + ((lq ^ swz(arow)) * 8);
    int b_idx[4];
    #pragma unroll
    for (int n = 0; n < 4; ++n) {
        int row = n * 16 + lj;
        b_idx[n] = row * 32 + ((lq ^ swz(row)) * 8);
    }

    f32x4 acc[4];
    #pragma unroll
    for (int n = 0; n < 4; ++n) acc[n] = (f32x4){0.f, 0.f, 0.f, 0.f};

    for (int step = 0; step < 32; ++step) {
        int i0 = step * 32;
        if (step) __syncthreads();
        {                                       // stage h^T: 1 chunk/thread
            int p = ac ^ swz(hd_r);
            union { short8 s8; __hip_bfloat16 bh[8]; } pk;
            #pragma unroll
            for (int e = 0; e < 8; ++e)
                pk.bh[e] = __float2bfloat16(hbp[(size_t)(i0 + ac * 8 + e) * HDD]);
            *reinterpret_cast<short8*>(&lha[hd_r * 32 + p * 8]) = pk.s8;
        }
        {                                       // stage P'^T: 1 chunk/thread (pure gather)
            int p = bc ^ swz(u_r);
            short8 pk;
            #pragma unroll
            for (int e = 0; e < 8; ++e)
                pk[e] = Pbp[(size_t)(i0 + bc * 8 + e) * LUU];
            *reinterpret_cast<short8*>(&lsa[u_r * 32 + p * 8]) = pk;
        }
        __syncthreads();
        short8 af = *reinterpret_cast<const short8*>(&lha[a_idx]);
        #pragma unroll
        for (int n = 0; n < 4; ++n) {
            short8 bf = *reinterpret_cast<const short8*>(&lsa[b_idx[n]]);
            acc[n] = __builtin_amdgcn_mfma_f32_16x16x32_bf16(af, bf, acc[n], 0, 0, 0);
        }
    }

    __hip_bfloat16* cbt = reinterpret_cast<__hip_bfloat16*>(ws + CBT_OFF);
    #pragma unroll
    for (int q = 0; q < 4; ++q) {
        int hd = hd0 + wave * 16 + lq * 4 + q;
        #pragma unroll
        for (int n = 0; n < 4; ++n) {
            int uu = n * 16 + lj;
            cbt[(size_t)(b * 256 + hd) * 128 + u0 + uu] =
                __float2bfloat16(acc[n][q] * um_s[uu]);
        }
    }
}

// ---------------- K4 (MFMA): U=a_t·u, H=b_t·C, concat output ----------------
// a_t = P'·um_j ; b_t = P'·R2_i·Cc_j with R2 = hm·e^{rm}/ri, Cc = e^{-cm}·ci
__global__ __launch_bounds__(256) void k_outm(const float* __restrict__ h,
                                              const void* __restrict__ h_mask,
                                              const void* __restrict__ u_mask,
                                              const float* __restrict__ ws,
                                              float* __restrict__ out) {
    __shared__ __align__(16) short la[64 * 32], lb[64 * 32];
    __shared__ __align__(16) short lu[128 * 32], lc[128 * 32];
    __shared__ float R2_l[64];
    __shared__ float um_l[128], Cc_l[128];

    int b = blockIdx.x, i0 = blockIdx.y * 64, hd0 = blockIdx.z * 128;
    int t = threadIdx.x;
    int flag = reinterpret_cast<const int*>(ws)[FLAG_OFF];
    int wave = t >> 6, lane = t & 63, lj = lane & 15, lq = lane >> 4;

    if (t < 64) {
        float rmv = ws[RM_OFF + b * LHH + i0 + t];
        float riv = ws[RI_OFF + b * LHH + i0 + t];
        R2_l[t] = mval(h_mask, b * LHH + i0 + t, flag) * cexpf(rmv) / riv;
    } else if (t < 192) {
        int j = t - 64;
        float cmv = ws[CM_OFF + b * LUU + j];
        Cc_l[j] = cexpf(-cmv) * ws[CI_OFF + b * LUU + j];
        um_l[j] = mval(u_mask, b * LUU + j, flag);
    }

    const short* Pbase = reinterpret_cast<const short*>(ws + P_OFF) + (size_t)b * LHH * LUU;
    const short* ubt = reinterpret_cast<const short*>(ws + UBT_OFF) + ((size_t)(b * 256 + hd0)) * 128;
    const short* cbt = reinterpret_cast<const short*>(ws + CBT_OFF) + ((size_t)(b * 256 + hd0)) * 128;

    int air = t >> 2, ap = t & 3;
    int brow = t >> 1;
    int a_idx = (wave * 16 + lj) * 32 + ((lq ^ swz(wave * 16 + lj)) * 8);
    int b_idx[8];
    #pragma unroll
    for (int n = 0; n < 8; ++n) {
        int r = n * 16 + lj;
        b_idx[n] = r * 32 + ((lq ^ swz(r)) * 8);
    }

    f32x4 aU[8], aH[8];
    #pragma unroll
    for (int n = 0; n < 8; ++n) { aU[n] = (f32x4){0,0,0,0}; aH[n] = (f32x4){0,0,0,0}; }

    for (int step = 0; step < 4; ++step) {
        int j0 = step * 32;
        __syncthreads();
        {
            int lgc = ap ^ swz(air);
            short8 pv8 = *reinterpret_cast<const short8*>(
                Pbase + (size_t)(i0 + air) * LUU + j0 + lgc * 8);
            float R2v = R2_l[air];
            union { short8 s8; __hip_bfloat16 bh[8]; } pa, pb;
            #pragma unroll
            for (int c = 0; c < 8; ++c) {
                int j = j0 + lgc * 8 + c;
                float p = b2f(pv8[c]);
                pa.bh[c] = __float2bfloat16(p * um_l[j]);
                pb.bh[c] = __float2bfloat16(p * R2v * Cc_l[j]);
            }
            *reinterpret_cast<short8*>(&la[air * 32 + ap * 8]) = pa.s8;
            *reinterpret_cast<short8*>(&lb[air * 32 + ap * 8]) = pb.s8;
        }
        #pragma unroll
        for (int pp = 0; pp < 2; ++pp) {
            int p = (t & 1) * 2 + pp;
            int lgc = p ^ swz(brow);
            *reinterpret_cast<short8*>(&lu[brow * 32 + p * 8]) =
                *reinterpret_cast<const short8*>(ubt + (size_t)brow * 128 + j0 + lgc * 8);
            *reinterpret_cast<short8*>(&lc[brow * 32 + p * 8]) =
                *reinterpret_cast<const short8*>(cbt + (size_t)brow * 128 + j0 + lgc * 8);
        }
        __syncthreads();
        short8 fa = *reinterpret_cast<const short8*>(&la[a_idx]);
        short8 fb = *reinterpret_cast<const short8*>(&lb[a_idx]);
        #pragma unroll
        for (int n = 0; n < 8; ++n) {
            short8 gu = *reinterpret_cast<const short8*>(&lu[b_idx[n]]);
            short8 gc = *reinterpret_cast<const short8*>(&lc[b_idx[n]]);
            aU[n] = __builtin_amdgcn_mfma_f32_16x16x32_bf16(fa, gu, aU[n], 0, 0, 0);
            aH[n] = __builtin_amdgcn_mfma_f32_16x16x32_bf16(fb, gc, aH[n], 0, 0, 0);
        }
    }

    #pragma unroll
    for (int n = 0; n < 8; ++n) {
        int hd = hd0 + n * 16 + lj;
        #pragma unroll
        for (int q = 0; q < 4; ++q) {
            int i = i0 + wave * 16 + lq * 4 + q;
            float hv = h[((size_t)(b * LHH + i)) * HDD + hd];
            size_t base = ((size_t)(b * LHH + i)) * (4 * HDD) + hd;
            float Uv = aU[n][q], Hv = aH[n][q];
            out[base]           = hv;
            out[base + HDD]     = Uv;
            out[base + 2 * HDD] = hv * Uv;
            out[base + 3 * HDD] = hv * Hv;
        }
    }
}

extern "C" void kernel_launch(void* const* d_in, const int* in_sizes, int n_in,
                              void* d_out, int out_size, void* d_ws, size_t ws_size,
                              hipStream_t stream) {
    const float* h = (const float*)d_in[0];
    const float* u = (const float*)d_in[1];
    const void*  h_mask = d_in[2];
    const void*  u_mask = d_in[3];
    const float* w    = (const float*)d_in[4];
    const float* bias = (const float*)d_in[5];
    float* ws  = (float*)d_ws;
    float* out = (float*)d_out;

    if (ws_size < WS_FLOATS * sizeof(float)) return;  // diagnostic: leaves out zeroed

    k_prep<<<dim3(BB, HDD / 32), 256, 0, stream>>>(u, w, (const unsigned char*)h_mask, ws);
    k_Smfma<<<dim3(BB, LHH / 64), 256, 0, stream>>>(h, u_mask, h_mask, bias, ws);
    k_Cmfma<<<dim3(BB, 4, 2), 256, 0, stream>>>(h, u_mask, ws);
    k_outm<<<dim3(BB, LHH / 64, 2), 256, 0, stream>>>(h, h_mask, u_mask, ws, out);
}